// Round 1
// 10798.134 us; speedup vs baseline: 1.7291x; 1.7291x over previous
//
#include <hip/hip_runtime.h>
#include <cmath>

namespace {
constexpr int B    = 256;
constexpr int T    = 1000;
constexpr int H    = 256;
constexpr int DIN  = 64;
constexpr int NC   = 10;
constexpr int BT   = 16;          // batch rows per WG
constexpr int NWG  = B / BT;      // 16 workgroups
// packed fragment regions, bf16 elements. Each HxH region: 8 ksl x 16 nt x 64 lane x 8 = 65536
constexpr int REG_SZ   = 65536;
constexpr int OFF_WFC  = 0;               // fused Wf1 @ W_in[:,1:]
constexpr int OFF_WGC  = 1 * REG_SZ;      // fused Wg1 @ Wn[:,1:]
constexpr int OFF_WF2  = 2 * REG_SZ;
constexpr int OFF_WG2  = 3 * REG_SZ;
constexpr int OFF_WD   = 4 * REG_SZ;      // 8 ksl x 4 nt x 64 x 8 = 16384
constexpr int TOTAL_PK = OFF_WD + 16384;  // 278528 bf16
constexpr int VEC_BYTES = 4096;           // 4 x 256 f32: wfc0, bfc, wgc0, bgc
}

typedef __attribute__((ext_vector_type(8))) short bf16x8;
typedef __attribute__((ext_vector_type(4))) float f32x4;
#define MFMA16(a, b, c) __builtin_amdgcn_mfma_f32_16x16x32_bf16(a, b, c, 0, 0, 0)

__device__ __forceinline__ unsigned short f32_to_bf16(float x) {
  unsigned int u = __float_as_uint(x);
  u = (u + 0x7FFFu + ((u >> 16) & 1u)) >> 16;   // RNE
  return (unsigned short)u;
}

// lgkm-only barrier: LDS writes visible, but VMEM (weights/noise/pred stores) stays in flight.
#define BAR() do {                                           \
    asm volatile("s_waitcnt lgkmcnt(0)" ::: "memory");       \
    __builtin_amdgcn_s_barrier();                            \
    asm volatile("" ::: "memory");                           \
  } while (0)

// ---------------- prep: fused first-stage weights + bias/time vectors ----------------
// Wfc[n][k] = sum_p Wf1[n][p] * W_in[p][1+k]   (and g-branch analog)
// vecs[0][n]=wfc0, vecs[1][n]=bfc, vecs[2][n]=wgc0, vecs[3][n]=bgc
__global__ void prep_fused(const float* __restrict__ Wf1, const float* __restrict__ W_in,
                           const float* __restrict__ b_in, const float* __restrict__ bf1,
                           const float* __restrict__ Wg1, const float* __restrict__ Wn,
                           const float* __restrict__ bn, const float* __restrict__ bg1,
                           unsigned short* __restrict__ pk, float* __restrict__ vecs) {
  int i = blockIdx.x * blockDim.x + threadIdx.x;
  if (i < 2 * REG_SZ) {
    int r = i >> 16, idx = i & (REG_SZ - 1);
    int j = idx & 7, lane = (idx >> 3) & 63, nt = (idx >> 9) & 15, s = idx >> 13;
    int n = nt * 16 + (lane & 15);
    int k = 32 * s + 8 * (lane >> 4) + j;
    const float* A  = r ? Wg1 : Wf1;
    const float* Bm = r ? Wn  : W_in;
    float acc = 0.f;
#pragma unroll 8
    for (int p = 0; p < H; ++p) acc += A[n * H + p] * Bm[p * 257 + 1 + k];
    pk[(r ? OFF_WGC : OFF_WFC) + idx] = f32_to_bf16(acc);
  } else if (i < 2 * REG_SZ + 4 * H) {
    int t = i - 2 * REG_SZ;
    int v = t >> 8, n = t & 255;
    float acc = 0.f;
    if (v == 0) {
#pragma unroll 8
      for (int p = 0; p < H; ++p) acc += Wf1[n * H + p] * W_in[p * 257];
    } else if (v == 1) {
      acc = bf1[n];
#pragma unroll 8
      for (int p = 0; p < H; ++p) acc += Wf1[n * H + p] * b_in[p];
    } else if (v == 2) {
#pragma unroll 8
      for (int p = 0; p < H; ++p) acc += Wg1[n * H + p] * Wn[p * 257];
    } else {
      acc = bg1[n];
#pragma unroll 8
      for (int p = 0; p < H; ++p) acc += Wg1[n * H + p] * bn[p];
    }
    vecs[v * 256 + n] = acc;
  }
}

// ---------------- pack Wf2 / Wg2 / Wd into B-fragment layout ----------------
__global__ void pack_frags(const float* __restrict__ Wf2, const float* __restrict__ Wg2,
                           const float* __restrict__ Wd, unsigned short* __restrict__ pk) {
  int i = blockIdx.x * blockDim.x + threadIdx.x;
  if (i < 2 * REG_SZ) {
    int r = i >> 16, idx = i & (REG_SZ - 1);
    int j = idx & 7, lane = (idx >> 3) & 63, nt = (idx >> 9) & 15, s = idx >> 13;
    int n = nt * 16 + (lane & 15);
    int k = 32 * s + 8 * (lane >> 4) + j;
    const float* W = r ? Wg2 : Wf2;
    pk[OFF_WF2 + i] = f32_to_bf16(W[n * 256 + k]);
  } else if (i < TOTAL_PK) {
    int idx = i - 2 * REG_SZ;
    int j = idx & 7, lane = (idx >> 3) & 63, nt = (idx >> 9) & 3, s = idx >> 11;
    int n = nt * 16 + (lane & 15);
    int k = 32 * s + 8 * (lane >> 4) + j;
    pk[OFF_WD + idx] = f32_to_bf16(Wd[n * 256 + k]);
  }
}

// ---------------- main scan: 16 WGs x 512 threads (8 waves), 2 stages / 2 barriers per step ----
__global__ void __launch_bounds__(512, 2)
sde_mfma(const float* __restrict__ coeffs, const float* __restrict__ times,
         const int* __restrict__ mask, const float* __restrict__ noise,
         const float* __restrict__ bf2, const float* __restrict__ bg2,
         const float* __restrict__ W0, const float* __restrict__ b0p,
         const float* __restrict__ bd, const float* __restrict__ Wc,
         const float* __restrict__ bc,
         const float* __restrict__ vecs,
         const unsigned short* __restrict__ wpack,
         float* __restrict__ pred, float* __restrict__ logits) {
  const int tid  = threadIdx.x;
  const int lane = tid & 63;
  const int w    = tid >> 6;          // wave 0..7
  const int c    = lane & 15;         // col within tile
  const int q4   = lane >> 4;         // quad
  const int rb   = blockIdx.x * BT;   // batch row base

  __shared__ __align__(16) short yA[8 * 64 * 8];
  __shared__ __align__(16) short uA[8 * 64 * 8];
  __shared__ __align__(16) short vA[8 * 64 * 8];
  __shared__ float zfin[BT * H];
  __shared__ float ybuf0[BT * H];
  __shared__ float x0buf[BT * DIN];
  __shared__ int   lastS[BT];

  const bf16x8* pk   = (const bf16x8*)wpack;
  const bf16x8* pWfc = pk + (OFF_WFC >> 3);
  const bf16x8* pWgc = pk + (OFF_WGC >> 3);
  const bf16x8* pWf2 = pk + (OFF_WF2 >> 3);
  const bf16x8* pWg2 = pk + (OFF_WG2 >> 3);
  const bf16x8* pWd  = pk + (OFF_WD  >> 3);
  const bf16x8* yAv  = (const bf16x8*)yA;
  const bf16x8* uAv  = (const bf16x8*)uA;
  const bf16x8* vAv  = (const bf16x8*)vA;

  // scatter one value into A-fragment layout
  auto scat = [&](short* buf, float v, int n, int m) {
    int s = n >> 5, off = n & 31, q = off >> 3, j = off & 7;
    buf[(s * 64 + q * 16 + m) * 8 + j] = (short)f32_to_bf16(v);
  };

  // ---- init: sequence lengths ----
  if (tid < BT) lastS[tid] = 0;
  __syncthreads();
  {
    int m = tid >> 5, sl = tid & 31;
    int cnt = 0;
    for (int i = sl; i < T; i += 32) cnt += mask[(rb + m) * T + i];
    atomicAdd(&lastS[m], cnt);
  }
  for (int i = tid; i < BT * DIN; i += 512) {
    int m = i >> 6, k = i & 63;
    x0buf[i] = coeffs[(size_t)(rb + m) * (T - 1) * (4 * DIN) + k];
  }
  __syncthreads();
  if (tid < BT) lastS[tid] -= 1;
  __syncthreads();

  // ---- y0 = x0 @ W0^T + b0 (scalar, one-time) ----
  for (int o = tid; o < BT * H; o += 512) {
    int m = o >> 8, n = o & 255;
    float acc = b0p[n];
#pragma unroll 8
    for (int k = 0; k < DIN; ++k) acc += x0buf[m * DIN + k] * W0[n * DIN + k];
    ybuf0[o] = acc;
  }
  __syncthreads();

  // ---- per-lane constants ----
  const int n0 = 32 * w + c, n1 = n0 + 16;
  const float wfc00 = vecs[0 * 256 + n0], wfc01 = vecs[0 * 256 + n1];
  const float bfc0  = vecs[1 * 256 + n0], bfc1  = vecs[1 * 256 + n1];
  const float wgc00 = vecs[2 * 256 + n0], wgc01 = vecs[2 * 256 + n1];
  const float bgc0  = vecs[3 * 256 + n0], bgc1  = vecs[3 * 256 + n1];
  const float bf2v0 = bf2[n0], bf2v1 = bf2[n1];
  const float bg2v0 = bg2[n0], bg2v1 = bg2[n1];
  const int   np    = w * 16 + c;                      // pred col (waves 0-3)
  const float bdv   = (w < 4) ? bd[np] : 0.f;
  int lst[4];
#pragma unroll
  for (int r = 0; r < 4; ++r) lst[r] = lastS[q4 * 4 + r];

  // ---- resident stage-B weights: Wf2/Wg2 slices, 32 frags = 128 VGPRs ----
  bf16x8 wbf[8][4];
#pragma unroll
  for (int s = 0; s < 8; ++s) {
    wbf[s][0] = pWf2[(s * 16 + 2 * w    ) * 64 + lane];
    wbf[s][1] = pWf2[(s * 16 + 2 * w + 1) * 64 + lane];
    wbf[s][2] = pWg2[(s * 16 + 2 * w    ) * 64 + lane];
    wbf[s][3] = pWg2[(s * 16 + 2 * w + 1) * 64 + lane];
  }

  // ---- y state into registers + yA frags + zfin(last==0) ----
  float yr[2][4];
#pragma unroll
  for (int tt = 0; tt < 2; ++tt)
#pragma unroll
    for (int r = 0; r < 4; ++r) {
      int m = q4 * 4 + r, n = 32 * w + 16 * tt + c;
      float v = ybuf0[m * H + n];
      yr[tt][r] = v;
      if (lst[r] == 0) zfin[m * H + n] = v;
      scat(yA, v, n, m);
    }
  __syncthreads();

  // ---- pred[:, 0, :] ----
  if (w < 4) {
    f32x4 acc = (f32x4){0.f, 0.f, 0.f, 0.f};
#pragma unroll
    for (int s = 0; s < 8; ++s)
      acc = MFMA16(yAv[s * 64 + lane], pWd[(s * 4 + w) * 64 + lane], acc);
#pragma unroll
    for (int r = 0; r < 4; ++r) {
      int m = q4 * 4 + r;
      pred[((size_t)(rb + m) * T + 0) * 64 + np] = acc[r] + bdv;
    }
  }

  // ---- prologue prefetch: noise for st=0, times ----
  float epc[2][4];
#pragma unroll
  for (int tt = 0; tt < 2; ++tt)
#pragma unroll
    for (int r = 0; r < 4; ++r) {
      int m = q4 * 4 + r, n = 32 * w + 16 * tt + c;
      epc[tt][r] = noise[((size_t)0 * B + rb + m) * H + n];
    }
  float tcur = times[0];
  float tnext = times[1];

  // ---- main scan: 2 barriers / step ----
  for (int st = 0; st < T - 1; ++st) {
    float dtv = tnext - tcur;
    float sdt = sqrtf(dtv);

    // ---- stage A: h_f = y@Wfc^T, h_g = y@Wgc^T; u,v = lipswish(h + b + t*w0) ----
    f32x4 af0 = (f32x4){0.f, 0.f, 0.f, 0.f}, af1 = af0, ag0 = af0, ag1 = af0;
#pragma unroll
    for (int s = 0; s < 8; ++s) {
      bf16x8 a = yAv[s * 64 + lane];
      af0 = MFMA16(a, pWfc[(s * 16 + 2 * w    ) * 64 + lane], af0);
      af1 = MFMA16(a, pWfc[(s * 16 + 2 * w + 1) * 64 + lane], af1);
      ag0 = MFMA16(a, pWgc[(s * 16 + 2 * w    ) * 64 + lane], ag0);
      ag1 = MFMA16(a, pWgc[(s * 16 + 2 * w + 1) * 64 + lane], ag1);
    }
#pragma unroll
    for (int r = 0; r < 4; ++r) {
      int m = q4 * 4 + r;
      float z0 = af0[r] + bfc0 + tcur * wfc00;
      float z1 = af1[r] + bfc1 + tcur * wfc01;
      float z2 = ag0[r] + bgc0 + tcur * wgc00;
      float z3 = ag1[r] + bgc1 + tcur * wgc01;
      scat(uA, 0.909f * z0 / (1.f + __expf(-z0)), n0, m);
      scat(uA, 0.909f * z1 / (1.f + __expf(-z1)), n1, m);
      scat(vA, 0.909f * z2 / (1.f + __expf(-z2)), n0, m);
      scat(vA, 0.909f * z3 / (1.f + __expf(-z3)), n1, m);
    }
    BAR();   // u/v exchange; VMEM stays in flight

    // ---- stage B: f = u@Wf2^T, g = v@Wg2^T (weights resident in VGPRs) ----
    f32x4 fc0 = (f32x4){0.f, 0.f, 0.f, 0.f}, fc1 = fc0, gc0 = fc0, gc1 = fc0;
#pragma unroll
    for (int s = 0; s < 8; ++s) {
      bf16x8 a1 = uAv[s * 64 + lane];
      bf16x8 a2 = vAv[s * 64 + lane];
      fc0 = MFMA16(a1, wbf[s][0], fc0);
      fc1 = MFMA16(a1, wbf[s][1], fc1);
      gc0 = MFMA16(a2, wbf[s][2], gc0);
      gc1 = MFMA16(a2, wbf[s][3], gc1);
    }

    // pred-weight prefetch: issue before the barrier so latency hides under update+barrier
    bf16x8 wdr[8];
    if (w < 4) {
#pragma unroll
      for (int s = 0; s < 8; ++s) wdr[s] = pWd[(s * 4 + w) * 64 + lane];
    }

    // ---- Euler-Maruyama update (fp32 state in regs) ----
#pragma unroll
    for (int r = 0; r < 4; ++r) {
      int m = q4 * 4 + r;
      float f0 = fc0[r] + bf2v0, f1 = fc1[r] + bf2v1;
      float g0 = gc0[r] + bg2v0, g1 = gc1[r] + bg2v1;
      float y0n = yr[0][r] + f0 * dtv + g0 * (sdt * epc[0][r]);
      float y1n = yr[1][r] + f1 * dtv + g1 * (sdt * epc[1][r]);
      yr[0][r] = y0n; yr[1][r] = y1n;
      if (st + 1 == lst[r]) { zfin[m * H + n0] = y0n; zfin[m * H + n1] = y1n; }
      scat(yA, y0n, n0, m);
      scat(yA, y1n, n1, m);
    }

    // prefetch next-step noise (full-step distance covers HBM latency)
    {
      int stn = (st + 1 < T - 1) ? st + 1 : T - 2;
#pragma unroll
      for (int tt = 0; tt < 2; ++tt)
#pragma unroll
        for (int r = 0; r < 4; ++r) {
          int m = q4 * 4 + r, n = 32 * w + 16 * tt + c;
          epc[tt][r] = noise[((size_t)stn * B + rb + m) * H + n];
        }
    }
    tcur = tnext;
    tnext = times[(st + 2 < T) ? st + 2 : T - 1];
    BAR();   // y exchange

    // ---- pred[:, st+1, :] = y_new @ Wd^T + bd (waves 0-3) ----
    if (w < 4) {
      f32x4 acc = (f32x4){0.f, 0.f, 0.f, 0.f};
#pragma unroll
      for (int s = 0; s < 8; ++s)
        acc = MFMA16(yAv[s * 64 + lane], wdr[s], acc);
#pragma unroll
      for (int r = 0; r < 4; ++r) {
        int m = q4 * 4 + r;
        pred[((size_t)(rb + m) * T + st + 1) * 64 + np] = acc[r] + bdv;
      }
    }
  }

  // ---- logits = z_final @ Wc^T + bc (fp32, one-time) ----
  __syncthreads();
  if (tid < BT * NC) {
    int m = tid / NC, cc = tid - m * NC;
    float acc = bc[cc];
#pragma unroll 8
    for (int k = 0; k < H; ++k) acc += zfin[m * H + k] * Wc[cc * H + k];
    logits[(rb + m) * NC + cc] = acc;
  }
}

extern "C" void kernel_launch(void* const* d_in, const int* in_sizes, int n_in,
                              void* d_out, int out_size, void* d_ws, size_t ws_size,
                              hipStream_t stream) {
  const float* coeffs = (const float*)d_in[0];
  const float* times  = (const float*)d_in[1];
  const int*   mask   = (const int*)d_in[2];
  const float* noise  = (const float*)d_in[3];
  const float* W_in   = (const float*)d_in[4];
  const float* b_in   = (const float*)d_in[5];
  const float* Wf1    = (const float*)d_in[6];
  const float* bf1    = (const float*)d_in[7];
  const float* Wf2    = (const float*)d_in[8];
  const float* bf2    = (const float*)d_in[9];
  const float* Wn     = (const float*)d_in[10];
  const float* bn     = (const float*)d_in[11];
  const float* Wg1    = (const float*)d_in[12];
  const float* bg1    = (const float*)d_in[13];
  const float* Wg2    = (const float*)d_in[14];
  const float* bg2    = (const float*)d_in[15];
  const float* W0     = (const float*)d_in[16];
  const float* b0p    = (const float*)d_in[17];
  const float* Wd     = (const float*)d_in[18];
  const float* bd     = (const float*)d_in[19];
  const float* Wc     = (const float*)d_in[20];
  const float* bc     = (const float*)d_in[21];

  float* vecs = (float*)d_ws;                                     // 4 KB
  unsigned short* wpack = (unsigned short*)((char*)d_ws + VEC_BYTES);  // 544 KB
  float* out    = (float*)d_out;
  float* pred   = out;                             // (B, T, 64)
  float* logits = out + (size_t)B * T * 64;        // (B, 10)

  hipLaunchKernelGGL(prep_fused, dim3((2 * REG_SZ + 4 * H + 255) / 256), dim3(256), 0, stream,
                     Wf1, W_in, b_in, bf1, Wg1, Wn, bn, bg1, wpack, vecs);
  hipLaunchKernelGGL(pack_frags, dim3((TOTAL_PK + 255) / 256), dim3(256), 0, stream,
                     Wf2, Wg2, Wd, wpack);
  hipLaunchKernelGGL(sde_mfma, dim3(NWG), dim3(512), 0, stream,
                     coeffs, times, mask, noise, bf2, bg2, W0, b0p, bd, Wc, bc,
                     vecs, wpack, pred, logits);
}